// Round 18
// baseline (220.384 us; speedup 1.0000x reference)
//
#include <hip/hip_runtime.h>
#include <hip/hip_bf16.h>

typedef __attribute__((ext_vector_type(8))) short s16x8;
typedef __attribute__((ext_vector_type(4))) float f32x4;
typedef __hip_bfloat16 bf16_t;

// ---------------------------------------------------------------- helpers
__device__ __forceinline__ void gload_lds16(const void* g, void* l) {
  __builtin_amdgcn_global_load_lds(
      (__attribute__((address_space(1))) void*)(g),
      (__attribute__((address_space(3))) void*)(l), 16, 0, 0);
}

__device__ __forceinline__ unsigned cvt_pk_bf16(float lo, float hi) {
  unsigned r;
  asm("v_cvt_pk_bf16_f32 %0, %1, %2" : "=v"(r) : "v"(lo), "v"(hi));
  return r;
}

// fast tanh: t=2^(2x*log2e); tanh = 1 - 2/(t+1).
__device__ __forceinline__ float fast_tanh(float x) {
  float t = exp2f(x * 2.885390082f);
  return 1.0f - 2.0f * __builtin_amdgcn_rcpf(t + 1.0f);
}

// ---------------------------------------------------------------- weight prep
__global__ void cast_all_k(const float* __restrict__ Wqkv, const float* __restrict__ Wout,
                           const float* __restrict__ W1, const float* __restrict__ W2,
                           bf16_t* __restrict__ Wqkv_bf, bf16_t* __restrict__ Wout_bf,
                           bf16_t* __restrict__ W1_bf, bf16_t* __restrict__ W2_bf) {
  int c = blockIdx.x * 256 + threadIdx.x;
  const float* src; bf16_t* dst; int off;
  if (c < 131072)      { src = Wqkv; dst = Wqkv_bf; off = c; }
  else if (c < 262144) { src = Wout; dst = Wout_bf; off = c - 131072; }
  else if (c < 786432) { src = W1;   dst = W1_bf;   off = c - 262144; }
  else                 { src = W2;   dst = W2_bf;   off = c - 786432; }
  int i = off * 8;
  float4 a = *(const float4*)(src + i);
  float4 b = *(const float4*)(src + i + 4);
  union { bf16_t h[8]; s16x8 v; } u;
  u.h[0] = __float2bfloat16(a.x); u.h[1] = __float2bfloat16(a.y);
  u.h[2] = __float2bfloat16(a.z); u.h[3] = __float2bfloat16(a.w);
  u.h[4] = __float2bfloat16(b.x); u.h[5] = __float2bfloat16(b.y);
  u.h[6] = __float2bfloat16(b.z); u.h[7] = __float2bfloat16(b.w);
  *(s16x8*)(dst + i) = u.v;
}

__global__ void reduce_kv_k(const float* __restrict__ Wqkv, bf16_t* __restrict__ Wred) {
  int d   = blockIdx.x & 63;
  int isv = blockIdx.x >> 6;
  int col = threadIdx.x * 4;
  const float* base = Wqkv + (size_t)(1024 + isv * 1024 + d) * 1024 + col;
  float4 s = {0.f, 0.f, 0.f, 0.f};
#pragma unroll
  for (int h = 0; h < 16; ++h) {
    float4 t = *(const float4*)(base + (size_t)h * 64 * 1024);
    s.x += t.x; s.y += t.y; s.z += t.z; s.w += t.w;
  }
  union { bf16_t h[4]; uint2 u; } o;
  o.h[0] = __float2bfloat16(s.x); o.h[1] = __float2bfloat16(s.y);
  o.h[2] = __float2bfloat16(s.z); o.h[3] = __float2bfloat16(s.w);
  *(uint2*)(Wred + (size_t)(isv * 64 + d) * 1024 + col) = o.u;
}

__global__ void bias_prep_k(const float* __restrict__ bqkv, float* __restrict__ br) {
  int i = blockIdx.x * 256 + threadIdx.x;
  if (i >= 1152) return;
  if (i < 1024) { br[i] = bqkv[i]; return; }
  int d = i - 1024;
  int off = (d < 64) ? (1024 + d) : (2048 + (d - 64));
  float s = 0.f;
#pragma unroll
  for (int h = 0; h < 16; ++h) s += bqkv[off + h * 64];
  br[i] = s;
}

// ---------------------------------------------------------------- layernorm + cast
__global__ __launch_bounds__(256) void ln_cast_k(const float* __restrict__ x,
                                                 const float* __restrict__ g,
                                                 const float* __restrict__ bb,
                                                 bf16_t* __restrict__ y) {
  int row = blockIdx.x, tid = threadIdx.x;
  float4 v = *(const float4*)(x + (size_t)row * 1024 + tid * 4);
  float s = v.x + v.y + v.z + v.w;
  float q = v.x * v.x + v.y * v.y + v.z * v.z + v.w * v.w;
#pragma unroll
  for (int off = 1; off < 64; off <<= 1) {
    s += __shfl_xor(s, off, 64);
    q += __shfl_xor(q, off, 64);
  }
  __shared__ float ss[4], qq[4];
  int wave = tid >> 6, lane = tid & 63;
  if (lane == 0) { ss[wave] = s; qq[wave] = q; }
  __syncthreads();
  s = ss[0] + ss[1] + ss[2] + ss[3];
  q = qq[0] + qq[1] + qq[2] + qq[3];
  float mu  = s * (1.0f / 1024.0f);
  float var = q * (1.0f / 1024.0f) - mu * mu;
  float rstd = rsqrtf(var + 1e-5f);
  float4 gg = *(const float4*)(g + tid * 4);
  float4 bv = *(const float4*)(bb + tid * 4);
  union { bf16_t h[4]; uint2 u; } o;
  o.h[0] = __float2bfloat16((v.x - mu) * rstd * gg.x + bv.x);
  o.h[1] = __float2bfloat16((v.y - mu) * rstd * gg.y + bv.y);
  o.h[2] = __float2bfloat16((v.z - mu) * rstd * gg.z + bv.z);
  o.h[3] = __float2bfloat16((v.w - mu) * rstd * gg.w + bv.w);
  *(uint2*)(y + (size_t)row * 1024 + tid * 4) = o.u;
}

// ---------------------------------------------------------------- GEMM 128x128 BK64
// v2 ledger on a 128^2 tile: vmcnt(0) -> barrier -> stage(t+1) flies across
// the whole tile. 64 KB LDS => 2 independent blocks/CU (two barrier domains
// overlap each other's drain+stage stalls; m103/m112: 128^2 beats 256^2 in
// 2-barrier-family loops). 4 waves (2Mx2N), per-wave 64x64 out, 32 MFMA +
// 16 ds_read_b128 per K-tile. Same verified swizzle algebra as gemm256-v2.
// EPI 2: fast-tanh -> bf16 (FC1); EPI 4: bf16 partial plane z (FC2 split-K)
template <int EPI>
__global__ __launch_bounds__(256) void gemm128(
    const bf16_t* __restrict__ A, const bf16_t* __restrict__ Bw,
    const float* __restrict__ bias, void* __restrict__ out0,
    int M, int N, int K, int Kslice) {
  __shared__ __align__(16) bf16_t As[2 * 8192];
  __shared__ __align__(16) bf16_t Bs[2 * 8192];
  const int tid  = threadIdx.x;
  const int lane = tid & 63;
  const int wave = tid >> 6;
  const int l15 = lane & 15, lg = lane >> 4;
  const int wm = wave >> 1, wn = wave & 1;

  // T1: bijective XCD swizzle over the flattened grid (nwg % 8 == 0)
  const unsigned nx = gridDim.x, ny = gridDim.y;
  unsigned fid = (blockIdx.z * ny + blockIdx.y) * nx + blockIdx.x;
  const unsigned nwg = nx * ny * gridDim.z;
  fid = (fid & 7) * (nwg >> 3) + (fid >> 3);
  const unsigned bxu = fid % nx;
  const unsigned rem = fid / nx;
  const unsigned byu = rem % ny;
  const unsigned bzu = rem / ny;
  const int bm = byu * 128, bn = bxu * 128;
  const size_t Kz = (size_t)K;
  const int kstart = bzu * Kslice;

  f32x4 acc[4][4];
#pragma unroll
  for (int f = 0; f < 4; ++f)
#pragma unroll
    for (int g = 0; g < 4; ++g) acc[f][g] = (f32x4){0.f, 0.f, 0.f, 0.f};

  const bf16_t* Ab = A + (size_t)bm * Kz + kstart;
  const bf16_t* Bb = Bw + (size_t)bn * Kz + kstart;

  // stage one BK=64 tile (A 128x64 + B 128x64, 16 KB each) = 8 gload instrs.
  // chunk c=(row,cpos): LDS holds global chunk cpos^(row&7); linear dst.
  auto stage = [&](int t, int buf) {
    const int k0 = t * 64;
#pragma unroll
    for (int j = 0; j < 4; ++j) {
      const int c   = j * 256 + tid;
      const int row = c >> 3;
      const int kc  = (c & 7) ^ (row & 7);
      gload_lds16(Ab + (size_t)row * Kz + k0 + kc * 8,
                  As + buf * 8192 + (j * 256 + wave * 64) * 8);
      gload_lds16(Bb + (size_t)row * Kz + k0 + kc * 8,
                  Bs + buf * 8192 + (j * 256 + wave * 64) * 8);
    }
  };

  const int NT = Kslice >> 6;
  stage(0, 0);
  int buf = 0;
  for (int t = 0; t < NT; ++t) {
    asm volatile("s_waitcnt vmcnt(0)" ::: "memory");   // stage(t) landed (1 tile old)
    __builtin_amdgcn_s_barrier();                      // all waves done with buf^1
    if (t + 1 < NT) stage(t + 1, buf ^ 1);             // flies across this tile
#pragma unroll
    for (int h = 0; h < 2; ++h) {
      s16x8 af[4], bfv[4];
#pragma unroll
      for (int f = 0; f < 4; ++f) {
        const int row = wm * 64 + f * 16 + l15;
        af[f] = *(const s16x8*)&As[buf * 8192 + (row * 8 + ((h * 4 + lg) ^ (l15 & 7))) * 8];
      }
#pragma unroll
      for (int g = 0; g < 4; ++g) {
        const int row = wn * 64 + g * 16 + l15;
        bfv[g] = *(const s16x8*)&Bs[buf * 8192 + (row * 8 + ((h * 4 + lg) ^ (l15 & 7))) * 8];
      }
      __builtin_amdgcn_s_setprio(1);
#pragma unroll
      for (int f = 0; f < 4; ++f)
#pragma unroll
        for (int g = 0; g < 4; ++g)
          acc[f][g] = __builtin_amdgcn_mfma_f32_16x16x32_bf16(af[f], bfv[g], acc[f][g], 0, 0, 0);
      __builtin_amdgcn_s_setprio(0);
    }
    buf ^= 1;
  }

#pragma unroll
  for (int f = 0; f < 4; ++f) {
    const int row0 = bm + wm * 64 + f * 16 + lg * 4;
#pragma unroll
    for (int g = 0; g < 4; ++g) {
      const int col = bn + wn * 64 + g * 16 + l15;
      const float bcol = (EPI == 4) ? 0.f : bias[col];
#pragma unroll
      for (int r = 0; r < 4; ++r) {
        const int rw = row0 + r;
        float c = acc[f][g][r] + bcol;
        if constexpr (EPI == 2) {
          ((bf16_t*)out0)[(size_t)rw * N + col] = __float2bfloat16(fast_tanh(c));
        } else {
          ((bf16_t*)out0)[((size_t)bzu * M + rw) * N + col] = __float2bfloat16(c);
        }
      }
    }
  }
}

// ---------------------------------------------------------------- GEMM 64x128 v2
// (frozen R15) barrier-top ledger; EPI0 q pre-scaled by 0.125*log2(e).
template <int EPI>
__global__ __launch_bounds__(256) void gemm64(
    const bf16_t* __restrict__ A, const bf16_t* __restrict__ Bw,
    const float* __restrict__ bias, void* __restrict__ out0,
    const float* __restrict__ resid, bf16_t* __restrict__ oks,
    bf16_t* __restrict__ ovt, int M, int N, int K) {
  __shared__ __align__(16) bf16_t As[2 * 64 * 32];
  __shared__ __align__(16) bf16_t Bs[2 * 128 * 32];
  const int tid  = threadIdx.x;
  const int lane = tid & 63;
  const int wave = tid >> 6;
  const int l15 = lane & 15, lg = lane >> 4;
  const int wr = (wave >> 1) * 32, wc = (wave & 1) * 64;
  const int bm = blockIdx.y * 64, bn = blockIdx.x * 128;
  const size_t Kz = (size_t)K;
  const int srow = lane >> 2;
  const int scol = ((lane & 3) ^ ((lane >> 3) & 3)) * 8;

  f32x4 acc[2][4];
#pragma unroll
  for (int m = 0; m < 2; ++m)
#pragma unroll
    for (int n = 0; n < 4; ++n) acc[m][n] = (f32x4){0.f, 0.f, 0.f, 0.f};

  const bf16_t* Ab = A + (size_t)bm * Kz;
  const bf16_t* Bb = Bw + (size_t)bn * Kz;

  auto stage = [&](int t, int buf) {
    const int k0 = t * 32;
    gload_lds16(Ab + (size_t)(wave * 16 + srow) * Kz + k0 + scol, As + buf * 2048 + wave * 512);
#pragma unroll
    for (int j = 0; j < 2; ++j) {
      const int cw = wave * 2 + j;
      gload_lds16(Bb + (size_t)(cw * 16 + srow) * Kz + k0 + scol, Bs + buf * 4096 + cw * 512);
    }
  };

  const int NT = K >> 5;
  const int rdoff = (lg ^ ((l15 >> 1) & 3)) * 8;
  stage(0, 0);
  int buf = 0;
  for (int t = 0; t < NT; ++t) {
    __syncthreads();
    if (t + 1 < NT) stage(t + 1, buf ^ 1);
    s16x8 af[2], bfv[4];
#pragma unroll
    for (int m = 0; m < 2; ++m)
      af[m] = *(const s16x8*)&As[buf * 2048 + (wr + m * 16 + l15) * 32 + rdoff];
#pragma unroll
    for (int n = 0; n < 4; ++n)
      bfv[n] = *(const s16x8*)&Bs[buf * 4096 + (wc + n * 16 + l15) * 32 + rdoff];
#pragma unroll
    for (int m = 0; m < 2; ++m)
#pragma unroll
      for (int n = 0; n < 4; ++n)
        acc[m][n] = __builtin_amdgcn_mfma_f32_16x16x32_bf16(af[m], bfv[n], acc[m][n], 0, 0, 0);
    buf ^= 1;
  }

#pragma unroll
  for (int m = 0; m < 2; ++m) {
    const int row0 = bm + wr + m * 16 + lg * 4;
#pragma unroll
    for (int n = 0; n < 4; ++n) {
      const int col = bn + wc + n * 16 + l15;
      const float bcol = bias[col];
#pragma unroll
      for (int r = 0; r < 4; ++r) {
        const int rw = row0 + r;
        float c = acc[m][n][r] + bcol;
        if constexpr (EPI == 0) {
          if (col < 1024) {
            ((bf16_t*)out0)[(size_t)rw * 1024 + col] =
                __float2bfloat16(c * 0.1803368801f);
          } else if (col < 1088) {
            int d = col - 1024, b = rw >> 11, t = rw & 2047;
            oks[((size_t)(b << 11) + t) * 64 + d] = __float2bfloat16(c);
          } else {
            int d = col - 1088, b = rw >> 11, t = rw & 2047;
            ovt[((size_t)b * 64 + d) * 2048 + t] = __float2bfloat16(c);
          }
        } else {
          ((float*)out0)[(size_t)rw * N + col] = c + resid[(size_t)rw * N + col];
        }
      }
    }
  }
}

// out = sum_z p[z] + bias  (FC2 split-K=4 combine, bf16 partials)
__global__ __launch_bounds__(256) void fc2_reduce_k(const bf16_t* __restrict__ p,
                                                    const float* __restrict__ bias,
                                                    float* __restrict__ out) {
  const size_t PL = (size_t)4096 * 1024;
  size_t i = ((size_t)blockIdx.x * 256 + threadIdx.x) * 8;
  float acc[8];
  {
    union { s16x8 v; bf16_t h[8]; } u;
    u.v = *(const s16x8*)(p + i);
#pragma unroll
    for (int j = 0; j < 8; ++j) acc[j] = __bfloat162float(u.h[j]);
  }
#pragma unroll
  for (int z = 1; z < 4; ++z) {
    union { s16x8 v; bf16_t h[8]; } u;
    u.v = *(const s16x8*)(p + z * PL + i);
#pragma unroll
    for (int j = 0; j < 8; ++j) acc[j] += __bfloat162float(u.h[j]);
  }
  const int col = (int)(i & 1023);
#pragma unroll
  for (int j = 0; j < 8; ++j) acc[j] += bias[col + j];
  *(float4*)(out + i)     = (float4){acc[0], acc[1], acc[2], acc[3]};
  *(float4*)(out + i + 4) = (float4){acc[4], acc[5], acc[6], acc[7]};
}

// ---------------------------------------------------------------- flash attention v8
// (frozen R17) t-range split into 2 half-range blocks per (b, p-octet) ->
// 1024 blocks, 50 KB LDS; partials merged by attn_combine_k.

template <bool MASK>
__device__ __forceinline__ void attn_tile(
    int t0, int p, const s16x8 (&qf)[2],
    const bf16_t* __restrict__ Ks, const bf16_t* __restrict__ Vs,
    bf16_t* __restrict__ Pl, int l15, int lg,
    float& m_run, float& l_part, f32x4 (&ao)[4]) {
  const int sw7 = l15 & 7;

  f32x4 sc[4];
#pragma unroll
  for (int n = 0; n < 4; ++n) sc[n] = (f32x4){0.f, 0.f, 0.f, 0.f};
#pragma unroll
  for (int ks2 = 0; ks2 < 2; ++ks2) {
#pragma unroll
    for (int n = 0; n < 4; ++n) {
      s16x8 kf = *(const s16x8*)&Ks[(n * 16 + l15) * 64 + (((ks2 << 2) | lg) ^ sw7) * 8];
      sc[n] = __builtin_amdgcn_mfma_f32_16x16x32_bf16(kf, qf[ks2], sc[n], 0, 0, 0);
    }
  }

  float mx = -1e30f;
#pragma unroll
  for (int n = 0; n < 4; ++n) {
#pragma unroll
    for (int r = 0; r < 4; ++r) {
      float v = sc[n][r];
      if (MASK && (t0 + n * 16 + lg * 4 + r > p)) v = -1e30f;
      sc[n][r] = v;
      mx = fmaxf(mx, v);
    }
  }
  if (__any(mx > m_run + 11.5f)) {
    float mxf = fmaxf(mx, __shfl_xor(mx, 16, 64));
    mxf = fmaxf(mxf, __shfl_xor(mxf, 32, 64));
    float mn = fmaxf(m_run, mxf);
    float alpha = exp2f(m_run - mn);
    m_run = mn;
    l_part *= alpha;
#pragma unroll
    for (int r = 0; r < 4; ++r) {
      float ar = __shfl(alpha, lg * 4 + r, 64);
#pragma unroll
      for (int n2 = 0; n2 < 4; ++n2) ao[n2][r] *= ar;
    }
  }
#pragma unroll
  for (int n = 0; n < 4; ++n) {
    float e0 = exp2f(sc[n][0] - m_run);
    float e1 = exp2f(sc[n][1] - m_run);
    float e2 = exp2f(sc[n][2] - m_run);
    float e3 = exp2f(sc[n][3] - m_run);
    l_part += (e0 + e1) + (e2 + e3);
    uint2 d;
    d.x = cvt_pk_bf16(e0, e1);
    d.y = cvt_pk_bf16(e2, e3);
    *(uint2*)&Pl[l15 * 72 + n * 16 + lg * 4] = d;
  }
#pragma unroll
  for (int ks2 = 0; ks2 < 2; ++ks2) {
    s16x8 pa = *(const s16x8*)&Pl[l15 * 72 + ks2 * 32 + lg * 8];
#pragma unroll
    for (int n2 = 0; n2 < 4; ++n2) {
      s16x8 vf = *(const s16x8*)&Vs[(n2 * 16 + l15) * 64 + (((ks2 << 2) | lg) ^ sw7) * 8];
      ao[n2] = __builtin_amdgcn_mfma_f32_16x16x32_bf16(pa, vf, ao[n2], 0, 0, 0);
    }
  }
}

__global__ __launch_bounds__(512) void attn_part_k(const bf16_t* __restrict__ q,
                                                   const bf16_t* __restrict__ ksp,
                                                   const bf16_t* __restrict__ vtp,
                                                   float* __restrict__ aoP,
                                                   float* __restrict__ mlP) {
  __shared__ __align__(16) bf16_t Ks[2 * 4096];
  __shared__ __align__(16) bf16_t Vs[2 * 4096];
  __shared__ __align__(16) bf16_t Plds[8][16 * 72];
  const int tid = threadIdx.x, lane = tid & 63, wave = tid >> 6;
  const int l15 = lane & 15, lg = lane >> 4;
  const int bi   = blockIdx.x;
  const int half = bi & 1;
  const int j    = bi >> 1;
  const int grp  = j & 255;
  const int b    = j >> 8;
  const int pbase = 2040 - 8 * grp;
  const int p = pbase + wave;
  const int plane = half * 2 + b;

  const bf16_t* qb_b = q   + (size_t)b * 32768 * 64;
  const bf16_t* ksb  = ksp + (size_t)b * 2048 * 64;
  const bf16_t* vtb  = vtp + (size_t)b * 64 * 2048;
  bf16_t* Pl = &Plds[wave][0];

  const int nst = (pbase + 71) >> 6;
  const int na  = (nst + 1) >> 1;
  const int lo  = half ? na : 0;
  const int hi  = half ? nst : na;

  const int srow = lane >> 3;
  const int scol = lane & 7;
  const int grow = wave * 8 + srow;
  const int gcol = scol ^ (grow & 7);
  const bf16_t* ksrc0 = ksb + (size_t)grow * 64 + gcol * 8;
  const bf16_t* vsrc0 = vtb + (size_t)grow * 2048 + gcol * 8;

  auto stageKV = [&](int t, int buf) {
    const int t0 = t * 64;
    gload_lds16(ksrc0 + (size_t)t0 * 64, Ks + buf * 4096 + wave * 512);
    gload_lds16(vsrc0 + t0, Vs + buf * 4096 + wave * 512);
  };

  s16x8 qf[2];
  {
    const bf16_t* qptr = qb_b + (size_t)(16 * p + l15) * 64;
    qf[0] = *(const s16x8*)(qptr + lg * 8);
    qf[1] = *(const s16x8*)(qptr + 32 + lg * 8);
  }

  float m_run = -1e30f, l_part = 0.f;
  f32x4 ao[4];
#pragma unroll
  for (int n = 0; n < 4; ++n) ao[n] = (f32x4){0.f, 0.f, 0.f, 0.f};

  if (lo < hi) {
    stageKV(lo, 0);
    int buf = 0;
    for (int tt = lo; tt < hi; ++tt) {
      asm volatile("s_waitcnt vmcnt(0)" ::: "memory");
      __builtin_amdgcn_s_barrier();
      if (tt + 1 < hi) stageKV(tt + 1, buf ^ 1);
      const int t0 = tt * 64;
      if (t0 <= p) {
        const bf16_t* Kc = Ks + buf * 4096;
        const bf16_t* Vc = Vs + buf * 4096;
        if (t0 + 63 <= p)
          attn_tile<false>(t0, p, qf, Kc, Vc, Pl, l15, lg, m_run, l_part, ao);
        else
          attn_tile<true>(t0, p, qf, Kc, Vc, Pl, l15, lg, m_run, l_part, ao);
      }
      buf ^= 1;
    }
  }

  float l2 = l_part + __shfl_xor(l_part, 16, 64);
  l2 += __shfl_xor(l2, 32, 64);

  float* aop = aoP + ((size_t)plane * 32768 + 16 * p) * 64;
#pragma unroll
  for (int n2 = 0; n2 < 4; ++n2) {
#pragma unroll
    for (int r = 0; r < 4; ++r) {
      aop[(size_t)(lg * 4 + r) * 64 + n2 * 16 + l15] = ao[n2][r];
    }
  }
  if (lg == 0) {
    float2* ml = (float2*)mlP;
    ml[(size_t)plane * 32768 + p * 16 + l15] = make_float2(m_run, l2);
  }
}

__global__ __launch_bounds__(256) void attn_combine_k(const float* __restrict__ aoP,
                                                      const float* __restrict__ mlP,
                                                      bf16_t* __restrict__ o) {
  const int gid = blockIdx.x * 256 + threadIdx.x;
  const int row = gid >> 3;
  const int seg = gid & 7;
  const int b   = row >> 15;
  const int r15 = row & 32767;
  const float2* ml = (const float2*)mlP;
  float2 mA = ml[(size_t)(0 * 2 + b) * 32768 + r15];
  float2 mB = ml[(size_t)(1 * 2 + b) * 32768 + r15];
  float ms = fmaxf(mA.x, mB.x);
  float fA = exp2f(mA.x - ms);
  float fB = exp2f(mB.x - ms);
  float li = 1.0f / (mA.y * fA + mB.y * fB);
  fA *= li; fB *= li;
  const float* pa = aoP + ((size_t)(0 * 2 + b) * 32768 + r15) * 64 + seg * 8;
  const float* pb = aoP + ((size_t)(1 * 2 + b) * 32768 + r15) * 64 + seg * 8;
  float4 a0 = *(const float4*)pa;
  float4 a1 = *(const float4*)(pa + 4);
  float4 b0 = *(const float4*)pb;
  float4 b1 = *(const float4*)(pb + 4);
  union { bf16_t h[8]; s16x8 v; } u;
  u.h[0] = __float2bfloat16(a0.x * fA + b0.x * fB);
  u.h[1] = __float2bfloat16(a0.y * fA + b0.y * fB);
  u.h[2] = __float2bfloat16(a0.z * fA + b0.z * fB);
  u.h[3] = __float2bfloat16(a0.w * fA + b0.w * fB);
  u.h[4] = __float2bfloat16(a1.x * fA + b1.x * fB);
  u.h[5] = __float2bfloat16(a1.y * fA + b1.y * fB);
  u.h[6] = __float2bfloat16(a1.z * fA + b1.z * fB);
  u.h[7] = __float2bfloat16(a1.w * fA + b1.w * fB);
  *(s16x8*)(o + (size_t)row * 64 + seg * 8) = u.v;
}

// ---------------------------------------------------------------- launch
extern "C" void kernel_launch(void* const* d_in, const int* in_sizes, int n_in,
                              void* d_out, int out_size, void* d_ws, size_t ws_size,
                              hipStream_t stream) {
  (void)in_sizes; (void)n_in; (void)out_size; (void)ws_size;
  const float* hidden = (const float*)d_in[0];
  const float* Wqkv   = (const float*)d_in[1];
  const float* bqkv   = (const float*)d_in[2];
  const float* Wout   = (const float*)d_in[3];
  const float* bout   = (const float*)d_in[4];
  const float* g1     = (const float*)d_in[5];
  const float* b1     = (const float*)d_in[6];
  const float* g2     = (const float*)d_in[7];
  const float* b2     = (const float*)d_in[8];
  const float* W1     = (const float*)d_in[9];
  const float* bfc1   = (const float*)d_in[10];
  const float* W2     = (const float*)d_in[11];
  const float* bfc2   = (const float*)d_in[12];

  float* out_h   = (float*)d_out;
  float* out_res = out_h + (size_t)4096 * 1024;

  char* ws = (char*)d_ws;
  auto alloc = [&](size_t bytes) {
    char* p = ws;
    ws += (bytes + 255) & ~(size_t)255;
    return p;
  };
  bf16_t* X1      = (bf16_t*)alloc((size_t)4096 * 1024 * 2);
  bf16_t* Wqkv_bf = (bf16_t*)alloc((size_t)1152 * 1024 * 2);
  float*  bias_r  = (float*)alloc(1152 * 4);
  bf16_t* qb      = (bf16_t*)alloc((size_t)4096 * 1024 * 2);
  bf16_t* ksum    = (bf16_t*)alloc((size_t)2 * 2048 * 64 * 2);
  bf16_t* vT      = (bf16_t*)alloc((size_t)2 * 64 * 2048 * 2);
  bf16_t* Ob      = (bf16_t*)alloc((size_t)4096 * 1024 * 2);
  bf16_t* Wout_bf = (bf16_t*)alloc((size_t)1024 * 1024 * 2);
  bf16_t* X2      = (bf16_t*)alloc((size_t)4096 * 1024 * 2);
  bf16_t* W1_bf   = (bf16_t*)alloc((size_t)4096 * 1024 * 2);
  bf16_t* W2_bf   = (bf16_t*)alloc((size_t)1024 * 4096 * 2);
  bf16_t* H1      = (bf16_t*)alloc((size_t)4096 * 4096 * 2);
  bf16_t* fc2_part = (bf16_t*)d_ws;   // aliases dead X1..X2 region at FC2 time
  float* aoP = (float*)H1;            // attn partials alias H1 (dead until FC1)
  float* mlP = (float*)X1;            // (m,l) partials alias X1 (dead after QKV)

  // weight prep
  cast_all_k<<<5120, 256, 0, stream>>>(Wqkv, Wout, W1, W2, Wqkv_bf, Wout_bf, W1_bf, W2_bf);
  reduce_kv_k<<<128, 256, 0, stream>>>(Wqkv, Wqkv_bf + (size_t)1024 * 1024);
  bias_prep_k<<<5, 256, 0, stream>>>(bqkv, bias_r);

  // LN1
  ln_cast_k<<<4096, 256, 0, stream>>>(hidden, g1, b1, X1);
  // QKV (reduced): M=4096, N=1152, K=1024
  gemm64<0><<<dim3(9, 64), 256, 0, stream>>>(X1, Wqkv_bf, bias_r, qb, nullptr, ksum, vT,
                                             4096, 1152, 1024);
  // attention v8: 1024 half-range blocks, then merge
  attn_part_k<<<1024, 512, 0, stream>>>(qb, ksum, vT, aoP, mlP);
  attn_combine_k<<<2048, 256, 0, stream>>>(aoP, mlP, Ob);
  // Wout + residual -> out_res (f32)
  gemm64<1><<<dim3(8, 64), 256, 0, stream>>>(Ob, Wout_bf, bout, out_res, hidden, nullptr,
                                             nullptr, 4096, 1024, 1024);
  // LN2
  ln_cast_k<<<4096, 256, 0, stream>>>(out_res, g2, b2, X2);
  // FC1 + tanh -- 128^2 BK=64, 1024 blocks -> 2 blocks/CU resident
  gemm128<2><<<dim3(32, 32), 256, 0, stream>>>(X2, W1_bf, bfc1, H1, 4096, 4096, 1024, 1024);
  // FC2 split-K=4 -> bf16 partials (1024 blocks), combine + bias
  gemm128<4><<<dim3(8, 32, 4), 256, 0, stream>>>(H1, W2_bf, nullptr, fc2_part,
                                                 4096, 1024, 4096, 1024);
  fc2_reduce_k<<<2048, 256, 0, stream>>>(fc2_part, bfc2, out_h);
}

// Round 19
// 205.758 us; speedup vs baseline: 1.0711x; 1.0711x over previous
//
#include <hip/hip_runtime.h>
#include <hip/hip_bf16.h>

typedef __attribute__((ext_vector_type(8))) short s16x8;
typedef __attribute__((ext_vector_type(4))) float f32x4;
typedef __hip_bfloat16 bf16_t;

// ---------------------------------------------------------------- helpers
__device__ __forceinline__ void gload_lds16(const void* g, void* l) {
  __builtin_amdgcn_global_load_lds(
      (__attribute__((address_space(1))) void*)(g),
      (__attribute__((address_space(3))) void*)(l), 16, 0, 0);
}

__device__ __forceinline__ unsigned cvt_pk_bf16(float lo, float hi) {
  unsigned r;
  asm("v_cvt_pk_bf16_f32 %0, %1, %2" : "=v"(r) : "v"(lo), "v"(hi));
  return r;
}

// fast tanh: t=2^(2x*log2e); tanh = 1 - 2/(t+1).
__device__ __forceinline__ float fast_tanh(float x) {
  float t = exp2f(x * 2.885390082f);
  return 1.0f - 2.0f * __builtin_amdgcn_rcpf(t + 1.0f);
}

// ---------------------------------------------------------------- weight prep
__global__ void cast_all_k(const float* __restrict__ Wqkv, const float* __restrict__ Wout,
                           const float* __restrict__ W1, const float* __restrict__ W2,
                           bf16_t* __restrict__ Wqkv_bf, bf16_t* __restrict__ Wout_bf,
                           bf16_t* __restrict__ W1_bf, bf16_t* __restrict__ W2_bf) {
  int c = blockIdx.x * 256 + threadIdx.x;
  const float* src; bf16_t* dst; int off;
  if (c < 131072)      { src = Wqkv; dst = Wqkv_bf; off = c; }
  else if (c < 262144) { src = Wout; dst = Wout_bf; off = c - 131072; }
  else if (c < 786432) { src = W1;   dst = W1_bf;   off = c - 262144; }
  else                 { src = W2;   dst = W2_bf;   off = c - 786432; }
  int i = off * 8;
  float4 a = *(const float4*)(src + i);
  float4 b = *(const float4*)(src + i + 4);
  union { bf16_t h[8]; s16x8 v; } u;
  u.h[0] = __float2bfloat16(a.x); u.h[1] = __float2bfloat16(a.y);
  u.h[2] = __float2bfloat16(a.z); u.h[3] = __float2bfloat16(a.w);
  u.h[4] = __float2bfloat16(b.x); u.h[5] = __float2bfloat16(b.y);
  u.h[6] = __float2bfloat16(b.z); u.h[7] = __float2bfloat16(b.w);
  *(s16x8*)(dst + i) = u.v;
}

__global__ void reduce_kv_k(const float* __restrict__ Wqkv, bf16_t* __restrict__ Wred) {
  int d   = blockIdx.x & 63;
  int isv = blockIdx.x >> 6;
  int col = threadIdx.x * 4;
  const float* base = Wqkv + (size_t)(1024 + isv * 1024 + d) * 1024 + col;
  float4 s = {0.f, 0.f, 0.f, 0.f};
#pragma unroll
  for (int h = 0; h < 16; ++h) {
    float4 t = *(const float4*)(base + (size_t)h * 64 * 1024);
    s.x += t.x; s.y += t.y; s.z += t.z; s.w += t.w;
  }
  union { bf16_t h[4]; uint2 u; } o;
  o.h[0] = __float2bfloat16(s.x); o.h[1] = __float2bfloat16(s.y);
  o.h[2] = __float2bfloat16(s.z); o.h[3] = __float2bfloat16(s.w);
  *(uint2*)(Wred + (size_t)(isv * 64 + d) * 1024 + col) = o.u;
}

__global__ void bias_prep_k(const float* __restrict__ bqkv, float* __restrict__ br) {
  int i = blockIdx.x * 256 + threadIdx.x;
  if (i >= 1152) return;
  if (i < 1024) { br[i] = bqkv[i]; return; }
  int d = i - 1024;
  int off = (d < 64) ? (1024 + d) : (2048 + (d - 64));
  float s = 0.f;
#pragma unroll
  for (int h = 0; h < 16; ++h) s += bqkv[off + h * 64];
  br[i] = s;
}

// ---------------------------------------------------------------- layernorm + cast
__global__ __launch_bounds__(256) void ln_cast_k(const float* __restrict__ x,
                                                 const float* __restrict__ g,
                                                 const float* __restrict__ bb,
                                                 bf16_t* __restrict__ y) {
  int row = blockIdx.x, tid = threadIdx.x;
  float4 v = *(const float4*)(x + (size_t)row * 1024 + tid * 4);
  float s = v.x + v.y + v.z + v.w;
  float q = v.x * v.x + v.y * v.y + v.z * v.z + v.w * v.w;
#pragma unroll
  for (int off = 1; off < 64; off <<= 1) {
    s += __shfl_xor(s, off, 64);
    q += __shfl_xor(q, off, 64);
  }
  __shared__ float ss[4], qq[4];
  int wave = tid >> 6, lane = tid & 63;
  if (lane == 0) { ss[wave] = s; qq[wave] = q; }
  __syncthreads();
  s = ss[0] + ss[1] + ss[2] + ss[3];
  q = qq[0] + qq[1] + qq[2] + qq[3];
  float mu  = s * (1.0f / 1024.0f);
  float var = q * (1.0f / 1024.0f) - mu * mu;
  float rstd = rsqrtf(var + 1e-5f);
  float4 gg = *(const float4*)(g + tid * 4);
  float4 bv = *(const float4*)(bb + tid * 4);
  union { bf16_t h[4]; uint2 u; } o;
  o.h[0] = __float2bfloat16((v.x - mu) * rstd * gg.x + bv.x);
  o.h[1] = __float2bfloat16((v.y - mu) * rstd * gg.y + bv.y);
  o.h[2] = __float2bfloat16((v.z - mu) * rstd * gg.z + bv.z);
  o.h[3] = __float2bfloat16((v.w - mu) * rstd * gg.w + bv.w);
  *(uint2*)(y + (size_t)row * 1024 + tid * 4) = o.u;
}

// ---------------------------------------------------------------- GEMM 256x256 v2
// (R12-proven) BK=64, 2 buffers, one drain+barrier per 64-K tile, 64-MFMA
// cluster under setprio, T2 swizzle both-sides, T1 XCD.
template <int EPI>
__global__ __launch_bounds__(512) void gemm256(
    const bf16_t* __restrict__ A, const bf16_t* __restrict__ Bw,
    const float* __restrict__ bias, void* __restrict__ out0,
    int M, int N, int K, int Kslice) {
  __shared__ __align__(16) bf16_t As[2 * 16384];
  __shared__ __align__(16) bf16_t Bs[2 * 16384];
  const int tid  = threadIdx.x;
  const int lane = tid & 63;
  const int wave = tid >> 6;
  const int l15 = lane & 15, lg = lane >> 4;
  const int wm = wave >> 2, wn = wave & 3;

  const unsigned nx = gridDim.x, ny = gridDim.y;
  unsigned fid = (blockIdx.z * ny + blockIdx.y) * nx + blockIdx.x;
  const unsigned nwg = nx * ny * gridDim.z;
  fid = (fid & 7) * (nwg >> 3) + (fid >> 3);
  const unsigned bxu = fid % nx;
  const unsigned rem = fid / nx;
  const unsigned byu = rem % ny;
  const unsigned bzu = rem / ny;
  const int bm = byu * 256, bn = bxu * 256;
  const size_t Kz = (size_t)K;
  const int kstart = bzu * Kslice;

  f32x4 acc[8][4];
#pragma unroll
  for (int f = 0; f < 8; ++f)
#pragma unroll
    for (int g = 0; g < 4; ++g) acc[f][g] = (f32x4){0.f, 0.f, 0.f, 0.f};

  const bf16_t* Ab = A + (size_t)bm * Kz + kstart;
  const bf16_t* Bb = Bw + (size_t)bn * Kz + kstart;

  auto stage = [&](int t, int buf) {
    const int k0 = t * 64;
#pragma unroll
    for (int j = 0; j < 4; ++j) {
      const int c   = j * 512 + tid;
      const int row = c >> 3;
      const int kc  = (c & 7) ^ (row & 7);
      gload_lds16(Ab + (size_t)row * Kz + k0 + kc * 8,
                  As + buf * 16384 + (j * 512 + wave * 64) * 8);
      gload_lds16(Bb + (size_t)row * Kz + k0 + kc * 8,
                  Bs + buf * 16384 + (j * 512 + wave * 64) * 8);
    }
  };

  const int NT = Kslice >> 6;
  stage(0, 0);
  int buf = 0;
  for (int t = 0; t < NT; ++t) {
    asm volatile("s_waitcnt vmcnt(0)" ::: "memory");   // stage(t) landed (1 tile old)
    __builtin_amdgcn_s_barrier();                      // all waves done with buf^1
    if (t + 1 < NT) stage(t + 1, buf ^ 1);             // flies across this tile
#pragma unroll
    for (int h = 0; h < 2; ++h) {
      s16x8 af[8], bfv[4];
#pragma unroll
      for (int f = 0; f < 8; ++f) {
        const int row = wm * 128 + f * 16 + l15;
        af[f] = *(const s16x8*)&As[buf * 16384 + (row * 8 + ((h * 4 + lg) ^ (l15 & 7))) * 8];
      }
#pragma unroll
      for (int g = 0; g < 4; ++g) {
        const int row = wn * 64 + g * 16 + l15;
        bfv[g] = *(const s16x8*)&Bs[buf * 16384 + (row * 8 + ((h * 4 + lg) ^ (l15 & 7))) * 8];
      }
      __builtin_amdgcn_s_setprio(1);
#pragma unroll
      for (int f = 0; f < 8; ++f)
#pragma unroll
        for (int g = 0; g < 4; ++g)
          acc[f][g] = __builtin_amdgcn_mfma_f32_16x16x32_bf16(af[f], bfv[g], acc[f][g], 0, 0, 0);
      __builtin_amdgcn_s_setprio(0);
    }
    buf ^= 1;
  }

#pragma unroll
  for (int f = 0; f < 8; ++f) {
    const int row0 = bm + wm * 128 + f * 16 + lg * 4;
#pragma unroll
    for (int g = 0; g < 4; ++g) {
      const int col = bn + wn * 64 + g * 16 + l15;
      const float bcol = (EPI == 4) ? 0.f : bias[col];
#pragma unroll
      for (int r = 0; r < 4; ++r) {
        const int rw = row0 + r;
        float c = acc[f][g][r] + bcol;
        if constexpr (EPI == 2) {
          ((bf16_t*)out0)[(size_t)rw * N + col] = __float2bfloat16(fast_tanh(c));
        } else {
          ((bf16_t*)out0)[((size_t)bzu * M + rw) * N + col] = __float2bfloat16(c);
        }
      }
    }
  }
}

// ---------------------------------------------------------------- GEMM 64x128 BK64
// v2 ledger port (R12 pattern): one vmcnt(0)+barrier per 64-K tile, stage(t+1)
// flies across the tile. 48 KB LDS. 4 waves, per-wave 32x64 out, 16 MFMA +
// 12 ds_read_b128 per tile. Swizzle: row stride 128B -> XOR chunk with row&7,
// pre-swizzled source (rule #21). EPI 0: QKV split (q pre-scaled); 1: +resid.
template <int EPI>
__global__ __launch_bounds__(256) void gemm64(
    const bf16_t* __restrict__ A, const bf16_t* __restrict__ Bw,
    const float* __restrict__ bias, void* __restrict__ out0,
    const float* __restrict__ resid, bf16_t* __restrict__ oks,
    bf16_t* __restrict__ ovt, int M, int N, int K) {
  __shared__ __align__(16) bf16_t As[2 * 4096];   // 64 x 64
  __shared__ __align__(16) bf16_t Bs[2 * 8192];   // 128 x 64
  const int tid  = threadIdx.x;
  const int lane = tid & 63;
  const int wave = tid >> 6;
  const int l15 = lane & 15, lg = lane >> 4;
  const int wr = (wave >> 1) * 32, wc = (wave & 1) * 64;
  const int bm = blockIdx.y * 64, bn = blockIdx.x * 128;
  const size_t Kz = (size_t)K;

  f32x4 acc[2][4];
#pragma unroll
  for (int m = 0; m < 2; ++m)
#pragma unroll
    for (int n = 0; n < 4; ++n) acc[m][n] = (f32x4){0.f, 0.f, 0.f, 0.f};

  const bf16_t* Ab = A + (size_t)bm * Kz;
  const bf16_t* Bb = Bw + (size_t)bn * Kz;

  // stage one BK=64 tile: A 64x64 (2 instrs), B 128x64 (4 instrs).
  // chunk c=(row,cpos): LDS holds global chunk cpos^(row&7); linear dst.
  auto stage = [&](int t, int buf) {
    const int k0 = t * 64;
#pragma unroll
    for (int j = 0; j < 2; ++j) {
      const int c   = j * 256 + tid;
      const int row = c >> 3;
      const int kc  = (c & 7) ^ (row & 7);
      gload_lds16(Ab + (size_t)row * Kz + k0 + kc * 8,
                  As + buf * 4096 + (j * 256 + wave * 64) * 8);
    }
#pragma unroll
    for (int j = 0; j < 4; ++j) {
      const int c   = j * 256 + tid;
      const int row = c >> 3;
      const int kc  = (c & 7) ^ (row & 7);
      gload_lds16(Bb + (size_t)row * Kz + k0 + kc * 8,
                  Bs + buf * 8192 + (j * 256 + wave * 64) * 8);
    }
  };

  const int NT = K >> 6;
  stage(0, 0);
  int buf = 0;
  for (int t = 0; t < NT; ++t) {
    asm volatile("s_waitcnt vmcnt(0)" ::: "memory");   // stage(t) landed (1 tile old)
    __builtin_amdgcn_s_barrier();                      // all waves done with buf^1
    if (t + 1 < NT) stage(t + 1, buf ^ 1);             // flies across this tile
#pragma unroll
    for (int h = 0; h < 2; ++h) {
      s16x8 af[2], bfv[4];
#pragma unroll
      for (int m = 0; m < 2; ++m) {
        const int row = wr + m * 16 + l15;
        af[m] = *(const s16x8*)&As[buf * 4096 + (row * 8 + ((h * 4 + lg) ^ (l15 & 7))) * 8];
      }
#pragma unroll
      for (int n = 0; n < 4; ++n) {
        const int row = wc + n * 16 + l15;
        bfv[n] = *(const s16x8*)&Bs[buf * 8192 + (row * 8 + ((h * 4 + lg) ^ (l15 & 7))) * 8];
      }
      __builtin_amdgcn_s_setprio(1);
#pragma unroll
      for (int m = 0; m < 2; ++m)
#pragma unroll
        for (int n = 0; n < 4; ++n)
          acc[m][n] = __builtin_amdgcn_mfma_f32_16x16x32_bf16(af[m], bfv[n], acc[m][n], 0, 0, 0);
      __builtin_amdgcn_s_setprio(0);
    }
    buf ^= 1;
  }

#pragma unroll
  for (int m = 0; m < 2; ++m) {
    const int row0 = bm + wr + m * 16 + lg * 4;
#pragma unroll
    for (int n = 0; n < 4; ++n) {
      const int col = bn + wc + n * 16 + l15;
      const float bcol = bias[col];
#pragma unroll
      for (int r = 0; r < 4; ++r) {
        const int rw = row0 + r;
        float c = acc[m][n][r] + bcol;
        if constexpr (EPI == 0) {
          if (col < 1024) {
            ((bf16_t*)out0)[(size_t)rw * 1024 + col] =
                __float2bfloat16(c * 0.1803368801f);   // fold 0.125*log2(e)
          } else if (col < 1088) {
            int d = col - 1024, b = rw >> 11, t = rw & 2047;
            oks[((size_t)(b << 11) + t) * 64 + d] = __float2bfloat16(c);
          } else {
            int d = col - 1088, b = rw >> 11, t = rw & 2047;
            ovt[((size_t)b * 64 + d) * 2048 + t] = __float2bfloat16(c);
          }
        } else {
          ((float*)out0)[(size_t)rw * N + col] = c + resid[(size_t)rw * N + col];
        }
      }
    }
  }
}

// out = sum_z p[z] + bias  (FC2 split-K=4 combine, bf16 partials)
__global__ __launch_bounds__(256) void fc2_reduce_k(const bf16_t* __restrict__ p,
                                                    const float* __restrict__ bias,
                                                    float* __restrict__ out) {
  const size_t PL = (size_t)4096 * 1024;
  size_t i = ((size_t)blockIdx.x * 256 + threadIdx.x) * 8;
  float acc[8];
  {
    union { s16x8 v; bf16_t h[8]; } u;
    u.v = *(const s16x8*)(p + i);
#pragma unroll
    for (int j = 0; j < 8; ++j) acc[j] = __bfloat162float(u.h[j]);
  }
#pragma unroll
  for (int z = 1; z < 4; ++z) {
    union { s16x8 v; bf16_t h[8]; } u;
    u.v = *(const s16x8*)(p + z * PL + i);
#pragma unroll
    for (int j = 0; j < 8; ++j) acc[j] += __bfloat162float(u.h[j]);
  }
  const int col = (int)(i & 1023);
#pragma unroll
  for (int j = 0; j < 8; ++j) acc[j] += bias[col + j];
  *(float4*)(out + i)     = (float4){acc[0], acc[1], acc[2], acc[3]};
  *(float4*)(out + i + 4) = (float4){acc[4], acc[5], acc[6], acc[7]};
}

// ---------------------------------------------------------------- flash attention v8
// (frozen R17) t-range split into 2 half-range blocks per (b, p-octet) ->
// 1024 blocks, 50 KB LDS; partials merged by attn_combine_k.

template <bool MASK>
__device__ __forceinline__ void attn_tile(
    int t0, int p, const s16x8 (&qf)[2],
    const bf16_t* __restrict__ Ks, const bf16_t* __restrict__ Vs,
    bf16_t* __restrict__ Pl, int l15, int lg,
    float& m_run, float& l_part, f32x4 (&ao)[4]) {
  const int sw7 = l15 & 7;

  f32x4 sc[4];
#pragma unroll
  for (int n = 0; n < 4; ++n) sc[n] = (f32x4){0.f, 0.f, 0.f, 0.f};
#pragma unroll
  for (int ks2 = 0; ks2 < 2; ++ks2) {
#pragma unroll
    for (int n = 0; n < 4; ++n) {
      s16x8 kf = *(const s16x8*)&Ks[(n * 16 + l15) * 64 + (((ks2 << 2) | lg) ^ sw7) * 8];
      sc[n] = __builtin_amdgcn_mfma_f32_16x16x32_bf16(kf, qf[ks2], sc[n], 0, 0, 0);
    }
  }

  float mx = -1e30f;
#pragma unroll
  for (int n = 0; n < 4; ++n) {
#pragma unroll
    for (int r = 0; r < 4; ++r) {
      float v = sc[n][r];
      if (MASK && (t0 + n * 16 + lg * 4 + r > p)) v = -1e30f;
      sc[n][r] = v;
      mx = fmaxf(mx, v);
    }
  }
  if (__any(mx > m_run + 11.5f)) {
    float mxf = fmaxf(mx, __shfl_xor(mx, 16, 64));
    mxf = fmaxf(mxf, __shfl_xor(mxf, 32, 64));
    float mn = fmaxf(m_run, mxf);
    float alpha = exp2f(m_run - mn);
    m_run = mn;
    l_part *= alpha;
#pragma unroll
    for (int r = 0; r < 4; ++r) {
      float ar = __shfl(alpha, lg * 4 + r, 64);
#pragma unroll
      for (int n2 = 0; n2 < 4; ++n2) ao[n2][r] *= ar;
    }
  }
#pragma unroll
  for (int n = 0; n < 4; ++n) {
    float e0 = exp2f(sc[n][0] - m_run);
    float e1 = exp2f(sc[n][1] - m_run);
    float e2 = exp2f(sc[n][2] - m_run);
    float e3 = exp2f(sc[n][3] - m_run);
    l_part += (e0 + e1) + (e2 + e3);
    uint2 d;
    d.x = cvt_pk_bf16(e0, e1);
    d.y = cvt_pk_bf16(e2, e3);
    *(uint2*)&Pl[l15 * 72 + n * 16 + lg * 4] = d;
  }
#pragma unroll
  for (int ks2 = 0; ks2 < 2; ++ks2) {
    s16x8 pa = *(const s16x8*)&Pl[l15 * 72 + ks2 * 32 + lg * 8];
#pragma unroll
    for (int n2 = 0; n2 < 4; ++n2) {
      s16x8 vf = *(const s16x8*)&Vs[(n2 * 16 + l15) * 64 + (((ks2 << 2) | lg) ^ sw7) * 8];
      ao[n2] = __builtin_amdgcn_mfma_f32_16x16x32_bf16(pa, vf, ao[n2], 0, 0, 0);
    }
  }
}

__global__ __launch_bounds__(512) void attn_part_k(const bf16_t* __restrict__ q,
                                                   const bf16_t* __restrict__ ksp,
                                                   const bf16_t* __restrict__ vtp,
                                                   float* __restrict__ aoP,
                                                   float* __restrict__ mlP) {
  __shared__ __align__(16) bf16_t Ks[2 * 4096];
  __shared__ __align__(16) bf16_t Vs[2 * 4096];
  __shared__ __align__(16) bf16_t Plds[8][16 * 72];
  const int tid = threadIdx.x, lane = tid & 63, wave = tid >> 6;
  const int l15 = lane & 15, lg = lane >> 4;
  const int bi   = blockIdx.x;
  const int half = bi & 1;
  const int j    = bi >> 1;
  const int grp  = j & 255;
  const int b    = j >> 8;
  const int pbase = 2040 - 8 * grp;
  const int p = pbase + wave;
  const int plane = half * 2 + b;

  const bf16_t* qb_b = q   + (size_t)b * 32768 * 64;
  const bf16_t* ksb  = ksp + (size_t)b * 2048 * 64;
  const bf16_t* vtb  = vtp + (size_t)b * 64 * 2048;
  bf16_t* Pl = &Plds[wave][0];

  const int nst = (pbase + 71) >> 6;
  const int na  = (nst + 1) >> 1;
  const int lo  = half ? na : 0;
  const int hi  = half ? nst : na;

  const int srow = lane >> 3;
  const int scol = lane & 7;
  const int grow = wave * 8 + srow;
  const int gcol = scol ^ (grow & 7);
  const bf16_t* ksrc0 = ksb + (size_t)grow * 64 + gcol * 8;
  const bf16_t* vsrc0 = vtb + (size_t)grow * 2048 + gcol * 8;

  auto stageKV = [&](int t, int buf) {
    const int t0 = t * 64;
    gload_lds16(ksrc0 + (size_t)t0 * 64, Ks + buf * 4096 + wave * 512);
    gload_lds16(vsrc0 + t0, Vs + buf * 4096 + wave * 512);
  };

  s16x8 qf[2];
  {
    const bf16_t* qptr = qb_b + (size_t)(16 * p + l15) * 64;
    qf[0] = *(const s16x8*)(qptr + lg * 8);
    qf[1] = *(const s16x8*)(qptr + 32 + lg * 8);
  }

  float m_run = -1e30f, l_part = 0.f;
  f32x4 ao[4];
#pragma unroll
  for (int n = 0; n < 4; ++n) ao[n] = (f32x4){0.f, 0.f, 0.f, 0.f};

  if (lo < hi) {
    stageKV(lo, 0);
    int buf = 0;
    for (int tt = lo; tt < hi; ++tt) {
      asm volatile("s_waitcnt vmcnt(0)" ::: "memory");
      __builtin_amdgcn_s_barrier();
      if (tt + 1 < hi) stageKV(tt + 1, buf ^ 1);
      const int t0 = tt * 64;
      if (t0 <= p) {
        const bf16_t* Kc = Ks + buf * 4096;
        const bf16_t* Vc = Vs + buf * 4096;
        if (t0 + 63 <= p)
          attn_tile<false>(t0, p, qf, Kc, Vc, Pl, l15, lg, m_run, l_part, ao);
        else
          attn_tile<true>(t0, p, qf, Kc, Vc, Pl, l15, lg, m_run, l_part, ao);
      }
      buf ^= 1;
    }
  }

  float l2 = l_part + __shfl_xor(l_part, 16, 64);
  l2 += __shfl_xor(l2, 32, 64);

  float* aop = aoP + ((size_t)plane * 32768 + 16 * p) * 64;
#pragma unroll
  for (int n2 = 0; n2 < 4; ++n2) {
#pragma unroll
    for (int r = 0; r < 4; ++r) {
      aop[(size_t)(lg * 4 + r) * 64 + n2 * 16 + l15] = ao[n2][r];
    }
  }
  if (lg == 0) {
    float2* ml = (float2*)mlP;
    ml[(size_t)plane * 32768 + p * 16 + l15] = make_float2(m_run, l2);
  }
}

__global__ __launch_bounds__(256) void attn_combine_k(const float* __restrict__ aoP,
                                                      const float* __restrict__ mlP,
                                                      bf16_t* __restrict__ o) {
  const int gid = blockIdx.x * 256 + threadIdx.x;
  const int row = gid >> 3;
  const int seg = gid & 7;
  const int b   = row >> 15;
  const int r15 = row & 32767;
  const float2* ml = (const float2*)mlP;
  float2 mA = ml[(size_t)(0 * 2 + b) * 32768 + r15];
  float2 mB = ml[(size_t)(1 * 2 + b) * 32768 + r15];
  float ms = fmaxf(mA.x, mB.x);
  float fA = exp2f(mA.x - ms);
  float fB = exp2f(mB.x - ms);
  float li = 1.0f / (mA.y * fA + mB.y * fB);
  fA *= li; fB *= li;
  const float* pa = aoP + ((size_t)(0 * 2 + b) * 32768 + r15) * 64 + seg * 8;
  const float* pb = aoP + ((size_t)(1 * 2 + b) * 32768 + r15) * 64 + seg * 8;
  float4 a0 = *(const float4*)pa;
  float4 a1 = *(const float4*)(pa + 4);
  float4 b0 = *(const float4*)pb;
  float4 b1 = *(const float4*)(pb + 4);
  union { bf16_t h[8]; s16x8 v; } u;
  u.h[0] = __float2bfloat16(a0.x * fA + b0.x * fB);
  u.h[1] = __float2bfloat16(a0.y * fA + b0.y * fB);
  u.h[2] = __float2bfloat16(a0.z * fA + b0.z * fB);
  u.h[3] = __float2bfloat16(a0.w * fA + b0.w * fB);
  u.h[4] = __float2bfloat16(a1.x * fA + b1.x * fB);
  u.h[5] = __float2bfloat16(a1.y * fA + b1.y * fB);
  u.h[6] = __float2bfloat16(a1.z * fA + b1.z * fB);
  u.h[7] = __float2bfloat16(a1.w * fA + b1.w * fB);
  *(s16x8*)(o + (size_t)row * 64 + seg * 8) = u.v;
}

// ---------------------------------------------------------------- launch
extern "C" void kernel_launch(void* const* d_in, const int* in_sizes, int n_in,
                              void* d_out, int out_size, void* d_ws, size_t ws_size,
                              hipStream_t stream) {
  (void)in_sizes; (void)n_in; (void)out_size; (void)ws_size;
  const float* hidden = (const float*)d_in[0];
  const float* Wqkv   = (const float*)d_in[1];
  const float* bqkv   = (const float*)d_in[2];
  const float* Wout   = (const float*)d_in[3];
  const float* bout   = (const float*)d_in[4];
  const float* g1     = (const float*)d_in[5];
  const float* b1     = (const float*)d_in[6];
  const float* g2     = (const float*)d_in[7];
  const float* b2     = (const float*)d_in[8];
  const float* W1     = (const float*)d_in[9];
  const float* bfc1   = (const float*)d_in[10];
  const float* W2     = (const float*)d_in[11];
  const float* bfc2   = (const float*)d_in[12];

  float* out_h   = (float*)d_out;
  float* out_res = out_h + (size_t)4096 * 1024;

  char* ws = (char*)d_ws;
  auto alloc = [&](size_t bytes) {
    char* p = ws;
    ws += (bytes + 255) & ~(size_t)255;
    return p;
  };
  bf16_t* X1      = (bf16_t*)alloc((size_t)4096 * 1024 * 2);
  bf16_t* Wqkv_bf = (bf16_t*)alloc((size_t)1152 * 1024 * 2);
  float*  bias_r  = (float*)alloc(1152 * 4);
  bf16_t* qb      = (bf16_t*)alloc((size_t)4096 * 1024 * 2);
  bf16_t* ksum    = (bf16_t*)alloc((size_t)2 * 2048 * 64 * 2);
  bf16_t* vT      = (bf16_t*)alloc((size_t)2 * 64 * 2048 * 2);
  bf16_t* Ob      = (bf16_t*)alloc((size_t)4096 * 1024 * 2);
  bf16_t* Wout_bf = (bf16_t*)alloc((size_t)1024 * 1024 * 2);
  bf16_t* X2      = (bf16_t*)alloc((size_t)4096 * 1024 * 2);
  bf16_t* W1_bf   = (bf16_t*)alloc((size_t)4096 * 1024 * 2);
  bf16_t* W2_bf   = (bf16_t*)alloc((size_t)1024 * 4096 * 2);
  bf16_t* H1      = (bf16_t*)alloc((size_t)4096 * 4096 * 2);
  bf16_t* fc2_part = (bf16_t*)d_ws;   // aliases dead X1..X2 region at FC2 time
  float* aoP = (float*)H1;            // attn partials alias H1 (dead until FC1)
  float* mlP = (float*)X1;            // (m,l) partials alias X1 (dead after QKV)

  // weight prep
  cast_all_k<<<5120, 256, 0, stream>>>(Wqkv, Wout, W1, W2, Wqkv_bf, Wout_bf, W1_bf, W2_bf);
  reduce_kv_k<<<128, 256, 0, stream>>>(Wqkv, Wqkv_bf + (size_t)1024 * 1024);
  bias_prep_k<<<5, 256, 0, stream>>>(bqkv, bias_r);

  // LN1
  ln_cast_k<<<4096, 256, 0, stream>>>(hidden, g1, b1, X1);
  // QKV (reduced): M=4096, N=1152, K=1024 -- gemm64 BK=64 v2
  gemm64<0><<<dim3(9, 64), 256, 0, stream>>>(X1, Wqkv_bf, bias_r, qb, nullptr, ksum, vT,
                                             4096, 1152, 1024);
  // attention v8: 1024 half-range blocks, then merge
  attn_part_k<<<1024, 512, 0, stream>>>(qb, ksum, vT, aoP, mlP);
  attn_combine_k<<<2048, 256, 0, stream>>>(aoP, mlP, Ob);
  // Wout + residual -> out_res (f32) -- gemm64 BK=64 v2
  gemm64<1><<<dim3(8, 64), 256, 0, stream>>>(Ob, Wout_bf, bout, out_res, hidden, nullptr,
                                             nullptr, 4096, 1024, 1024);
  // LN2
  ln_cast_k<<<4096, 256, 0, stream>>>(out_res, g2, b2, X2);
  // FC1 + tanh -- 256^2 BK=64 v2 (R12-proven), 256 blocks
  gemm256<2><<<dim3(16, 16), 512, 0, stream>>>(X2, W1_bf, bfc1, H1, 4096, 4096, 1024, 1024);
  // FC2 split-K=4 -> bf16 partials (256 blocks), combine + bias
  gemm256<4><<<dim3(4, 16, 4), 512, 0, stream>>>(H1, W2_bf, nullptr, fc2_part,
                                                 4096, 1024, 4096, 1024);
  fc2_reduce_k<<<2048, 256, 0, stream>>>(fc2_part, bfc2, out_h);
}